// Round 1
// baseline (307.038 us; speedup 1.0000x reference)
//
#include <hip/hip_runtime.h>

#define NV   500000
#define ND   64
#define NH   4
#define NHID 256
#define NS   10000
#define NOUT 128

// ---------------------------------------------------------------------------
// Kernel A: scores[v][h] = sum_{j=0..63} (e_v . Wv[:, h*64+j])^2
// Block: 256 threads, 64 elements. LDS: Et[64][68] (elem-major, padded),
// Wt[64][64] (k-major, per-head slice). Thread tile: 4 elems x 4 cols.
// ---------------------------------------------------------------------------
__global__ __launch_bounds__(256) void score_kernel(
    const float* __restrict__ emb, const float* __restrict__ Wv,
    float* __restrict__ scores)
{
    __shared__ float Et[64][68];
    __shared__ float Wt[64][64];
    const int t = threadIdx.x;
    const int base = blockIdx.x * 64;

    // stage embeddings tile (coalesced float4 loads)
    {
        const int r0 = t >> 4;        // 0..15
        const int c4 = (t & 15) << 2; // 0,4,...,60
#pragma unroll
        for (int it = 0; it < 4; ++it) {
            const int row = r0 + (it << 4);
            const int v = base + row;
            float4 val = make_float4(0.f, 0.f, 0.f, 0.f);
            if (v < NV)
                val = *reinterpret_cast<const float4*>(emb + (size_t)v * ND + c4);
            *reinterpret_cast<float4*>(&Et[row][c4]) = val;
        }
    }

    const int er = t >> 4;   // 0..15 (element group: elems 4*er..4*er+3)
    const int jc = t & 15;   // 0..15 (col group: cols 4*jc..4*jc+3)

    for (int h = 0; h < NH; ++h) {
        __syncthreads();   // protect Et (h==0) / Wt reuse (h>0)
        // stage Wv slice for head h: Wt[k][j] = Wv[k][h*64+j]
#pragma unroll
        for (int it = 0; it < 4; ++it) {
            const int k = (t >> 4) + (it << 4);
            const int j4 = (t & 15) << 2;
            *reinterpret_cast<float4*>(&Wt[k][j4]) =
                *reinterpret_cast<const float4*>(Wv + (size_t)k * NHID + h * 64 + j4);
        }
        __syncthreads();

        float acc[4][4] = {{0.f,0.f,0.f,0.f},{0.f,0.f,0.f,0.f},
                           {0.f,0.f,0.f,0.f},{0.f,0.f,0.f,0.f}};
#pragma unroll 4
        for (int k = 0; k < 64; ++k) {
            const float4 w = *reinterpret_cast<const float4*>(&Wt[k][jc << 2]);
            const float e0 = Et[(er << 2) + 0][k];
            const float e1 = Et[(er << 2) + 1][k];
            const float e2 = Et[(er << 2) + 2][k];
            const float e3 = Et[(er << 2) + 3][k];
            acc[0][0] = fmaf(e0, w.x, acc[0][0]); acc[0][1] = fmaf(e0, w.y, acc[0][1]);
            acc[0][2] = fmaf(e0, w.z, acc[0][2]); acc[0][3] = fmaf(e0, w.w, acc[0][3]);
            acc[1][0] = fmaf(e1, w.x, acc[1][0]); acc[1][1] = fmaf(e1, w.y, acc[1][1]);
            acc[1][2] = fmaf(e1, w.z, acc[1][2]); acc[1][3] = fmaf(e1, w.w, acc[1][3]);
            acc[2][0] = fmaf(e2, w.x, acc[2][0]); acc[2][1] = fmaf(e2, w.y, acc[2][1]);
            acc[2][2] = fmaf(e2, w.z, acc[2][2]); acc[2][3] = fmaf(e2, w.w, acc[2][3]);
            acc[3][0] = fmaf(e3, w.x, acc[3][0]); acc[3][1] = fmaf(e3, w.y, acc[3][1]);
            acc[3][2] = fmaf(e3, w.z, acc[3][2]); acc[3][3] = fmaf(e3, w.w, acc[3][3]);
        }
        // per-element partial sum of squares over this thread's 4 cols,
        // then reduce over the 16 jc threads (lane bits 0..3)
#pragma unroll
        for (int m = 0; m < 4; ++m) {
            float sq = acc[m][0]*acc[m][0] + acc[m][1]*acc[m][1]
                     + acc[m][2]*acc[m][2] + acc[m][3]*acc[m][3];
#pragma unroll
            for (int off = 1; off < 16; off <<= 1)
                sq += __shfl_xor(sq, off, 64);
            if (jc == 0) {
                const int v = base + (er << 2) + m;
                if (v < NV) scores[(size_t)v * NH + h] = sq;
            }
        }
    }
}

// ---------------------------------------------------------------------------
// Kernel B: segment boundaries from the SORTED map. start[s] = first v with
// map[v] >= s; start[NS] = NV. Segment s is [start[s], start[s+1]).
// ---------------------------------------------------------------------------
__global__ void bounds_kernel(const int* __restrict__ map, int* __restrict__ start)
{
    const int v = blockIdx.x * blockDim.x + threadIdx.x;
    if (v >= NV) return;
    const int cur = map[v];
    if (v == 0) {
        for (int s = 0; s <= cur; ++s) start[s] = 0;
    } else {
        const int prev = map[v - 1];
        for (int s = prev + 1; s <= cur; ++s) start[s] = v;
    }
    if (v == NV - 1) {
        for (int s = cur + 1; s <= NS; ++s) start[s] = NV;
    }
}

// ---------------------------------------------------------------------------
// Kernel C: per-sample softmax + weighted pooling.
// One 256-thread block per sample. scex holds scores on entry and is
// overwritten with exp(score - max) (same thread reads then writes each v).
// pooled[s][h*64+d] = (sum_v eexp[v][h]*emb[v][d]) / ssum[h]
// ---------------------------------------------------------------------------
__global__ __launch_bounds__(256) void pool_kernel(
    const float* __restrict__ emb, float* __restrict__ scex,
    const int* __restrict__ start, float* __restrict__ pooled)
{
    const int s = blockIdx.x;
    const int t = threadIdx.x;
    const int st = start[s];
    const int en = start[s + 1];
    const int n = en - st;
    if (n <= 0) { pooled[(size_t)s * NHID + t] = 0.f; return; }

    __shared__ float redm[4][4];  // [wave][head] partial max
    __shared__ float reds[4][4];  // [wave][head] partial sum
    const int wave = t >> 6;
    const int lane = t & 63;

    // ---- pass 1: per-head max ----
    float4 mx = make_float4(-1e30f, -1e30f, -1e30f, -1e30f);
    for (int v = st + t; v < en; v += 256) {
        const float4 sc = *reinterpret_cast<const float4*>(scex + (size_t)v * NH);
        mx.x = fmaxf(mx.x, sc.x); mx.y = fmaxf(mx.y, sc.y);
        mx.z = fmaxf(mx.z, sc.z); mx.w = fmaxf(mx.w, sc.w);
    }
#pragma unroll
    for (int off = 1; off < 64; off <<= 1) {
        mx.x = fmaxf(mx.x, __shfl_xor(mx.x, off, 64));
        mx.y = fmaxf(mx.y, __shfl_xor(mx.y, off, 64));
        mx.z = fmaxf(mx.z, __shfl_xor(mx.z, off, 64));
        mx.w = fmaxf(mx.w, __shfl_xor(mx.w, off, 64));
    }
    if (lane == 0) {
        redm[wave][0] = mx.x; redm[wave][1] = mx.y;
        redm[wave][2] = mx.z; redm[wave][3] = mx.w;
    }
    __syncthreads();
    float4 M;
    M.x = fmaxf(fmaxf(redm[0][0], redm[1][0]), fmaxf(redm[2][0], redm[3][0]));
    M.y = fmaxf(fmaxf(redm[0][1], redm[1][1]), fmaxf(redm[2][1], redm[3][1]));
    M.z = fmaxf(fmaxf(redm[0][2], redm[1][2]), fmaxf(redm[2][2], redm[3][2]));
    M.w = fmaxf(fmaxf(redm[0][3], redm[1][3]), fmaxf(redm[2][3], redm[3][3]));

    // ---- pass 2: exp + sum (in-place scores -> eexp) ----
    float4 sm = make_float4(0.f, 0.f, 0.f, 0.f);
    for (int v = st + t; v < en; v += 256) {
        const float4 sc = *reinterpret_cast<const float4*>(scex + (size_t)v * NH);
        float4 e;
        e.x = __expf(sc.x - M.x); e.y = __expf(sc.y - M.y);
        e.z = __expf(sc.z - M.z); e.w = __expf(sc.w - M.w);
        *reinterpret_cast<float4*>(scex + (size_t)v * NH) = e;
        sm.x += e.x; sm.y += e.y; sm.z += e.z; sm.w += e.w;
    }
#pragma unroll
    for (int off = 1; off < 64; off <<= 1) {
        sm.x += __shfl_xor(sm.x, off, 64);
        sm.y += __shfl_xor(sm.y, off, 64);
        sm.z += __shfl_xor(sm.z, off, 64);
        sm.w += __shfl_xor(sm.w, off, 64);
    }
    if (lane == 0) {
        reds[wave][0] = sm.x; reds[wave][1] = sm.y;
        reds[wave][2] = sm.z; reds[wave][3] = sm.w;
    }
    __syncthreads();   // also makes pass-2 global writes visible block-wide

    // ---- pass 3: weighted pooling; thread = (head, dim) ----
    const int h = t >> 6;
    const int d = t & 63;
    const float inv = 1.0f / (reds[0][h] + reds[1][h] + reds[2][h] + reds[3][h]);
    float acc = 0.f;
    int v = st;
    for (; v + 2 <= en; v += 2) {
        const float p0 = scex[(size_t)v * NH + h];
        const float p1 = scex[(size_t)(v + 1) * NH + h];
        const float g0 = emb[(size_t)v * ND + d];
        const float g1 = emb[(size_t)(v + 1) * ND + d];
        acc = fmaf(p0, g0, acc);
        acc = fmaf(p1, g1, acc);
    }
    if (v < en)
        acc = fmaf(scex[(size_t)v * NH + h], emb[(size_t)v * ND + d], acc);
    pooled[(size_t)s * NHID + t] = acc * inv;
}

// ---------------------------------------------------------------------------
// Kernel D: out[s][o] = sum_k pooled[s][k] * Wout[k][o]
// 16 samples per block; thread = (2 samples, 4 cols).
// ---------------------------------------------------------------------------
__global__ __launch_bounds__(256) void out_kernel(
    const float* __restrict__ pooled, const float* __restrict__ Wout,
    float* __restrict__ out)
{
    __shared__ float Pt[16][260];
    const int t = threadIdx.x;
    const int sbase = blockIdx.x << 4;
#pragma unroll
    for (int it = 0; it < 4; ++it) {
        const int idx = t + (it << 8);      // 0..1023
        const int row = idx >> 6;           // 0..15
        const int c4 = (idx & 63) << 2;     // 0..252
        *reinterpret_cast<float4*>(&Pt[row][c4]) =
            *reinterpret_cast<const float4*>(pooled + (size_t)(sbase + row) * NHID + c4);
    }
    __syncthreads();
    const int oc = (t & 31) << 2;   // output col base: 0..124
    const int sg = t >> 5;          // 0..7 -> samples 2sg, 2sg+1
    float a0x = 0.f, a0y = 0.f, a0z = 0.f, a0w = 0.f;
    float a1x = 0.f, a1y = 0.f, a1z = 0.f, a1w = 0.f;
#pragma unroll 4
    for (int k = 0; k < NHID; ++k) {
        const float4 w = *reinterpret_cast<const float4*>(Wout + (size_t)k * NOUT + oc);
        const float p0 = Pt[(sg << 1) + 0][k];
        const float p1 = Pt[(sg << 1) + 1][k];
        a0x = fmaf(p0, w.x, a0x); a0y = fmaf(p0, w.y, a0y);
        a0z = fmaf(p0, w.z, a0z); a0w = fmaf(p0, w.w, a0w);
        a1x = fmaf(p1, w.x, a1x); a1y = fmaf(p1, w.y, a1y);
        a1z = fmaf(p1, w.z, a1z); a1w = fmaf(p1, w.w, a1w);
    }
    float4 r0 = make_float4(a0x, a0y, a0z, a0w);
    float4 r1 = make_float4(a1x, a1y, a1z, a1w);
    *reinterpret_cast<float4*>(out + (size_t)(sbase + (sg << 1) + 0) * NOUT + oc) = r0;
    *reinterpret_cast<float4*>(out + (size_t)(sbase + (sg << 1) + 1) * NOUT + oc) = r1;
}

// ---------------------------------------------------------------------------
extern "C" void kernel_launch(void* const* d_in, const int* in_sizes, int n_in,
                              void* d_out, int out_size, void* d_ws, size_t ws_size,
                              hipStream_t stream)
{
    const float* emb  = (const float*)d_in[0];
    const float* Wv   = (const float*)d_in[1];
    const float* Wout = (const float*)d_in[2];
    const int*   map  = (const int*)d_in[3];
    float* out = (float*)d_out;

    char* ws = (char*)d_ws;
    float* scores = (float*)ws;                       // NV*4 floats   =  8,000,000 B
    float* pooled = (float*)(ws + 8000000);           // NS*256 floats = 10,240,000 B
    int*   start  = (int*)(ws + 18240000);            // (NS+1) ints

    score_kernel<<<(NV + 63) / 64, 256, 0, stream>>>(emb, Wv, scores);
    bounds_kernel<<<(NV + 255) / 256, 256, 0, stream>>>(map, start);
    pool_kernel<<<NS, 256, 0, stream>>>(emb, scores, start, pooled);
    out_kernel<<<NS / 16, 256, 0, stream>>>(pooled, Wout, out);
}

// Round 2
// 146.016 us; speedup vs baseline: 2.1028x; 2.1028x over previous
//
#include <hip/hip_runtime.h>

#define NV   500000
#define ND   64
#define NH   4
#define NHID 256
#define NS   10000
#define NOUT 128
#define NVT  (NV / 16)        // 31250 row-tiles of 16
#define SCORE_GRID 3125       // divides NVT exactly (10 iters/block)

typedef __attribute__((ext_vector_type(8))) _Float16 f16x8;
typedef __attribute__((ext_vector_type(4))) _Float16 f16x4;
typedef __attribute__((ext_vector_type(4))) float    f32x4;

// ---------------------------------------------------------------------------
// Kernel W: split W_v into f16 hi/lo, transposed: Wt[j][k] = Wv[k][j]
// grid 64 (=k), block 256 (=j). Coalesced reads, scattered tiny writes.
// ---------------------------------------------------------------------------
__global__ __launch_bounds__(256) void wconv_kernel(
    const float* __restrict__ Wv, _Float16* __restrict__ WtH,
    _Float16* __restrict__ WtL)
{
    const int k = blockIdx.x;        // 0..63
    const int j = threadIdx.x;       // 0..255
    const float w = Wv[k * NHID + j];
    const _Float16 hi = (_Float16)w;
    const _Float16 lo = (_Float16)(w - (float)hi);
    WtH[j * ND + k] = hi;
    WtL[j * ND + k] = lo;
}

// ---------------------------------------------------------------------------
// Kernel A: scores[v][h] = sum_j (e_v . Wv[:,h*64+j])^2 via split-f16 MFMA.
// C = Wt(A) x embT(B): C[j][v]. Wave w handles head w; W frags in registers.
// emb tile (16 rows x 64 k) staged fp32->hi/lo f16 in LDS, double-buffered,
// XOR-swizzled so frag ds_read_b128 is conflict-free.
// ---------------------------------------------------------------------------
__global__ __launch_bounds__(256) void score_kernel(
    const float* __restrict__ emb,
    const _Float16* __restrict__ WtH, const _Float16* __restrict__ WtL,
    float* __restrict__ scores)
{
    __shared__ _Float16 EH[2][16 * 64];
    __shared__ _Float16 EL[2][16 * 64];

    const int t    = threadIdx.x;
    const int lane = t & 63;
    const int h    = t >> 6;          // wave id == head
    const int vcol = lane & 15;       // v within tile (MFMA col)
    const int g    = lane >> 4;       // k-group

    // ---- W fragments for head h (registers, loaded once, L2-hot) ----
    f16x8 wh[4][2], wl[4][2];
#pragma unroll
    for (int jt = 0; jt < 4; ++jt)
#pragma unroll
        for (int ks = 0; ks < 2; ++ks) {
            const int j = h * 64 + jt * 16 + vcol;
            const size_t off = (size_t)j * ND + ks * 32 + g * 8;
            wh[jt][ks] = *reinterpret_cast<const f16x8*>(WtH + off);
            wl[jt][ks] = *reinterpret_cast<const f16x8*>(WtL + off);
        }

    // staging geometry: thread reads 4 floats of emb
    const int srow = t >> 4;          // 0..15
    const int sk4  = (t & 15) << 2;   // 0..60
    // LDS byte offset for the 8B hi/lo write (XOR swizzle on 16B units by row)
    const int woff = (srow << 7) + (((sk4 << 1)) ^ ((srow & 7) << 4));
    // frag read byte offsets (16B per lane), swizzle keyed by v
    const int voff0 = (vcol << 7) + (((0 << 6) | (g << 4)) ^ ((vcol & 7) << 4));
    const int voff1 = (vcol << 7) + (((1 << 6) | (g << 4)) ^ ((vcol & 7) << 4));

    int vt = blockIdx.x;
    // prologue: stage tile vt into buf 0
    {
        const float4 x = *reinterpret_cast<const float4*>(
            emb + (size_t)vt * 1024 + srow * 64 + sk4);
        f16x4 hv, lv;
        const float xa[4] = {x.x, x.y, x.z, x.w};
#pragma unroll
        for (int i = 0; i < 4; ++i) {
            const _Float16 hh = (_Float16)xa[i];
            hv[i] = hh;
            lv[i] = (_Float16)(xa[i] - (float)hh);
        }
        *reinterpret_cast<f16x4*>((char*)EH[0] + woff) = hv;
        *reinterpret_cast<f16x4*>((char*)EL[0] + woff) = lv;
    }
    __syncthreads();

    int buf = 0;
    while (vt < NVT) {
        const int vnext = vt + (int)gridDim.x;
        const bool hn = vnext < NVT;
        float4 x;
        if (hn)   // issue next tile's global load early (hide under MFMA)
            x = *reinterpret_cast<const float4*>(
                emb + (size_t)vnext * 1024 + srow * 64 + sk4);

        // ---- compute from buf ----
        f16x8 bh[2], bl[2];
        bh[0] = *reinterpret_cast<const f16x8*>((const char*)EH[buf] + voff0);
        bh[1] = *reinterpret_cast<const f16x8*>((const char*)EH[buf] + voff1);
        bl[0] = *reinterpret_cast<const f16x8*>((const char*)EL[buf] + voff0);
        bl[1] = *reinterpret_cast<const f16x8*>((const char*)EL[buf] + voff1);

        float s = 0.f;
#pragma unroll
        for (int jt = 0; jt < 4; ++jt) {
            f32x4 acc = {0.f, 0.f, 0.f, 0.f};
#pragma unroll
            for (int ks = 0; ks < 2; ++ks) {
                acc = __builtin_amdgcn_mfma_f32_16x16x32_f16(wh[jt][ks], bh[ks], acc, 0, 0, 0);
                acc = __builtin_amdgcn_mfma_f32_16x16x32_f16(wh[jt][ks], bl[ks], acc, 0, 0, 0);
                acc = __builtin_amdgcn_mfma_f32_16x16x32_f16(wl[jt][ks], bh[ks], acc, 0, 0, 0);
            }
            s += acc[0]*acc[0] + acc[1]*acc[1] + acc[2]*acc[2] + acc[3]*acc[3];
        }
        s += __shfl_xor(s, 16, 64);
        s += __shfl_xor(s, 32, 64);
        if (lane < 16)
            scores[(size_t)(vt * 16 + lane) * NH + h] = s;

        // ---- stage next tile into buf^1 ----
        if (hn) {
            f16x4 hv, lv;
            const float xa[4] = {x.x, x.y, x.z, x.w};
#pragma unroll
            for (int i = 0; i < 4; ++i) {
                const _Float16 hh = (_Float16)xa[i];
                hv[i] = hh;
                lv[i] = (_Float16)(xa[i] - (float)hh);
            }
            *reinterpret_cast<f16x4*>((char*)EH[buf ^ 1] + woff) = hv;
            *reinterpret_cast<f16x4*>((char*)EL[buf ^ 1] + woff) = lv;
        }
        __syncthreads();
        buf ^= 1;
        vt = vnext;
    }
}

// ---------------------------------------------------------------------------
// Kernel B: segment boundaries from the SORTED map.
// ---------------------------------------------------------------------------
__global__ void bounds_kernel(const int* __restrict__ map, int* __restrict__ start)
{
    const int v = blockIdx.x * blockDim.x + threadIdx.x;
    if (v >= NV) return;
    const int cur = map[v];
    if (v == 0) {
        for (int s = 0; s <= cur; ++s) start[s] = 0;
    } else {
        const int prev = map[v - 1];
        for (int s = prev + 1; s <= cur; ++s) start[s] = v;
    }
    if (v == NV - 1) {
        for (int s = cur + 1; s <= NS; ++s) start[s] = NV;
    }
}

// ---------------------------------------------------------------------------
// Kernel C: per-sample softmax + weighted pooling. One block per sample.
// ---------------------------------------------------------------------------
__global__ __launch_bounds__(256) void pool_kernel(
    const float* __restrict__ emb, float* __restrict__ scex,
    const int* __restrict__ start, float* __restrict__ pooled)
{
    const int s = blockIdx.x;
    const int t = threadIdx.x;
    const int st = start[s];
    const int en = start[s + 1];
    const int n = en - st;
    if (n <= 0) { pooled[(size_t)s * NHID + t] = 0.f; return; }

    __shared__ float redm[4][4];
    __shared__ float reds[4][4];
    const int wave = t >> 6;
    const int lane = t & 63;

    float4 mx = make_float4(-1e30f, -1e30f, -1e30f, -1e30f);
    for (int v = st + t; v < en; v += 256) {
        const float4 sc = *reinterpret_cast<const float4*>(scex + (size_t)v * NH);
        mx.x = fmaxf(mx.x, sc.x); mx.y = fmaxf(mx.y, sc.y);
        mx.z = fmaxf(mx.z, sc.z); mx.w = fmaxf(mx.w, sc.w);
    }
#pragma unroll
    for (int off = 1; off < 64; off <<= 1) {
        mx.x = fmaxf(mx.x, __shfl_xor(mx.x, off, 64));
        mx.y = fmaxf(mx.y, __shfl_xor(mx.y, off, 64));
        mx.z = fmaxf(mx.z, __shfl_xor(mx.z, off, 64));
        mx.w = fmaxf(mx.w, __shfl_xor(mx.w, off, 64));
    }
    if (lane == 0) {
        redm[wave][0] = mx.x; redm[wave][1] = mx.y;
        redm[wave][2] = mx.z; redm[wave][3] = mx.w;
    }
    __syncthreads();
    float4 M;
    M.x = fmaxf(fmaxf(redm[0][0], redm[1][0]), fmaxf(redm[2][0], redm[3][0]));
    M.y = fmaxf(fmaxf(redm[0][1], redm[1][1]), fmaxf(redm[2][1], redm[3][1]));
    M.z = fmaxf(fmaxf(redm[0][2], redm[1][2]), fmaxf(redm[2][2], redm[3][2]));
    M.w = fmaxf(fmaxf(redm[0][3], redm[1][3]), fmaxf(redm[2][3], redm[3][3]));

    float4 sm = make_float4(0.f, 0.f, 0.f, 0.f);
    for (int v = st + t; v < en; v += 256) {
        const float4 sc = *reinterpret_cast<const float4*>(scex + (size_t)v * NH);
        float4 e;
        e.x = __expf(sc.x - M.x); e.y = __expf(sc.y - M.y);
        e.z = __expf(sc.z - M.z); e.w = __expf(sc.w - M.w);
        *reinterpret_cast<float4*>(scex + (size_t)v * NH) = e;
        sm.x += e.x; sm.y += e.y; sm.z += e.z; sm.w += e.w;
    }
#pragma unroll
    for (int off = 1; off < 64; off <<= 1) {
        sm.x += __shfl_xor(sm.x, off, 64);
        sm.y += __shfl_xor(sm.y, off, 64);
        sm.z += __shfl_xor(sm.z, off, 64);
        sm.w += __shfl_xor(sm.w, off, 64);
    }
    if (lane == 0) {
        reds[wave][0] = sm.x; reds[wave][1] = sm.y;
        reds[wave][2] = sm.z; reds[wave][3] = sm.w;
    }
    __syncthreads();

    const int h = t >> 6;
    const int d = t & 63;
    const float inv = 1.0f / (reds[0][h] + reds[1][h] + reds[2][h] + reds[3][h]);
    float acc = 0.f;
    int v = st;
    for (; v + 2 <= en; v += 2) {
        const float p0 = scex[(size_t)v * NH + h];
        const float p1 = scex[(size_t)(v + 1) * NH + h];
        const float g0 = emb[(size_t)v * ND + d];
        const float g1 = emb[(size_t)(v + 1) * ND + d];
        acc = fmaf(p0, g0, acc);
        acc = fmaf(p1, g1, acc);
    }
    if (v < en)
        acc = fmaf(scex[(size_t)v * NH + h], emb[(size_t)v * ND + d], acc);
    pooled[(size_t)s * NHID + t] = acc * inv;
}

// ---------------------------------------------------------------------------
// Kernel D: out = pooled @ W_out
// ---------------------------------------------------------------------------
__global__ __launch_bounds__(256) void out_kernel(
    const float* __restrict__ pooled, const float* __restrict__ Wout,
    float* __restrict__ out)
{
    __shared__ float Pt[16][260];
    const int t = threadIdx.x;
    const int sbase = blockIdx.x << 4;
#pragma unroll
    for (int it = 0; it < 4; ++it) {
        const int idx = t + (it << 8);
        const int row = idx >> 6;
        const int c4 = (idx & 63) << 2;
        *reinterpret_cast<float4*>(&Pt[row][c4]) =
            *reinterpret_cast<const float4*>(pooled + (size_t)(sbase + row) * NHID + c4);
    }
    __syncthreads();
    const int oc = (t & 31) << 2;
    const int sg = t >> 5;
    float a0x = 0.f, a0y = 0.f, a0z = 0.f, a0w = 0.f;
    float a1x = 0.f, a1y = 0.f, a1z = 0.f, a1w = 0.f;
#pragma unroll 4
    for (int k = 0; k < NHID; ++k) {
        const float4 w = *reinterpret_cast<const float4*>(Wout + (size_t)k * NOUT + oc);
        const float p0 = Pt[(sg << 1) + 0][k];
        const float p1 = Pt[(sg << 1) + 1][k];
        a0x = fmaf(p0, w.x, a0x); a0y = fmaf(p0, w.y, a0y);
        a0z = fmaf(p0, w.z, a0z); a0w = fmaf(p0, w.w, a0w);
        a1x = fmaf(p1, w.x, a1x); a1y = fmaf(p1, w.y, a1y);
        a1z = fmaf(p1, w.z, a1z); a1w = fmaf(p1, w.w, a1w);
    }
    *reinterpret_cast<float4*>(out + (size_t)(sbase + (sg << 1) + 0) * NOUT + oc) =
        make_float4(a0x, a0y, a0z, a0w);
    *reinterpret_cast<float4*>(out + (size_t)(sbase + (sg << 1) + 1) * NOUT + oc) =
        make_float4(a1x, a1y, a1z, a1w);
}

// ---------------------------------------------------------------------------
extern "C" void kernel_launch(void* const* d_in, const int* in_sizes, int n_in,
                              void* d_out, int out_size, void* d_ws, size_t ws_size,
                              hipStream_t stream)
{
    const float* emb  = (const float*)d_in[0];
    const float* Wv   = (const float*)d_in[1];
    const float* Wout = (const float*)d_in[2];
    const int*   map  = (const int*)d_in[3];
    float* out = (float*)d_out;

    char* ws = (char*)d_ws;
    float*     scores = (float*)ws;                    //  8,000,000 B
    float*     pooled = (float*)(ws + 8000000);        // 10,240,000 B
    int*       start  = (int*)(ws + 18240000);         //     40,004 B
    _Float16*  WtH    = (_Float16*)(ws + 18280064);    //     32,768 B
    _Float16*  WtL    = (_Float16*)(ws + 18312832);    //     32,768 B

    wconv_kernel<<<64, 256, 0, stream>>>(Wv, WtH, WtL);
    score_kernel<<<SCORE_GRID, 256, 0, stream>>>(emb, WtH, WtL, scores);
    bounds_kernel<<<(NV + 255) / 256, 256, 0, stream>>>(map, start);
    pool_kernel<<<NS, 256, 0, stream>>>(emb, scores, start, pooled);
    out_kernel<<<NS / 16, 256, 0, stream>>>(pooled, Wout, out);
}

// Round 3
// 107.537 us; speedup vs baseline: 2.8552x; 1.3578x over previous
//
#include <hip/hip_runtime.h>

#define NV    500000
#define ND    64
#define NH    4
#define NHID  256
#define NS    10000
#define NOUT  128
#define GSAMP 4                 // samples per block
#define FUSED_GRID (NS / GSAMP) // 2500

typedef __attribute__((ext_vector_type(8))) _Float16 f16x8;
typedef __attribute__((ext_vector_type(4))) _Float16 f16x4;
typedef __attribute__((ext_vector_type(4))) float    f32x4;

// ---------------------------------------------------------------------------
// Kernel W: split W_v into f16 hi/lo, transposed: Wt[j][k] = Wv[k][j]
// ---------------------------------------------------------------------------
__global__ __launch_bounds__(256) void wconv_kernel(
    const float* __restrict__ Wv, _Float16* __restrict__ WtH,
    _Float16* __restrict__ WtL)
{
    const int k = blockIdx.x;        // 0..63
    const int j = threadIdx.x;       // 0..255
    const float w = Wv[k * NHID + j];
    const _Float16 hi = (_Float16)w;
    const _Float16 lo = (_Float16)(w - (float)hi);
    WtH[j * ND + k] = hi;
    WtL[j * ND + k] = lo;
}

// ---------------------------------------------------------------------------
// Kernel B: segment boundaries from the SORTED map.
// ---------------------------------------------------------------------------
__global__ void bounds_kernel(const int* __restrict__ map, int* __restrict__ start)
{
    const int v = blockIdx.x * blockDim.x + threadIdx.x;
    if (v >= NV) return;
    const int cur = map[v];
    if (v == 0) {
        for (int s = 0; s <= cur; ++s) start[s] = 0;
    } else {
        const int prev = map[v - 1];
        for (int s = prev + 1; s <= cur; ++s) start[s] = v;
    }
    if (v == NV - 1) {
        for (int s = cur + 1; s <= NS; ++s) start[s] = NV;
    }
}

// ---------------------------------------------------------------------------
// Fused kernel: per sample -> scores (split-f16 MFMA) -> online softmax ->
// weighted pooling, reading emb from HBM exactly once.
// Block = 256 threads (4 waves, wave h = head h). GSAMP samples per block.
// Chunked over segment rows, C<=64 rows staged in LDS.
// ---------------------------------------------------------------------------
__global__ __launch_bounds__(256, 4) void fused_kernel(
    const float* __restrict__ emb,
    const _Float16* __restrict__ WtH, const _Float16* __restrict__ WtL,
    const int* __restrict__ start, float* __restrict__ pooled)
{
    __shared__ _Float16 EH[64 * 64];   // emb hi, swizzled rows
    __shared__ _Float16 EL[64 * 64];   // emb lo, swizzled rows
    __shared__ float    EF[64 * 64];   // emb fp32 (pool source)
    __shared__ float    escore[NH][64];
    __shared__ float    ee[NH][64];

    const int t    = threadIdx.x;
    const int lane = t & 63;
    const int h    = t >> 6;          // wave id == head
    const int vcol = lane & 15;       // MFMA col (v within 16-tile)
    const int g    = lane >> 4;       // k-group

    // ---- W fragments for head h (registers, L2-hot) ----
    f16x8 wh[4][2], wl[4][2];
#pragma unroll
    for (int jt = 0; jt < 4; ++jt)
#pragma unroll
        for (int ks = 0; ks < 2; ++ks) {
            const int j = (h << 6) + (jt << 4) + vcol;
            const size_t off = ((size_t)j << 6) + (ks << 5) + (g << 3);
            wh[jt][ks] = *reinterpret_cast<const f16x8*>(WtH + off);
            wl[jt][ks] = *reinterpret_cast<const f16x8*>(WtL + off);
        }

    for (int si = 0; si < GSAMP; ++si) {
        const int s  = blockIdx.x * GSAMP + si;
        const int st = start[s];
        const int en = start[s + 1];

        float acc = 0.f;        // pooled accum for (h, d=lane)
        float m = -1e30f;       // running max (per head, lane-replicated)
        float l = 0.f;          // running denom

        for (int c0 = st; c0 < en; c0 += 64) {
            const int C = min(64, en - c0);

            // ---- stage chunk: fp32 copy + hi/lo f16 swizzled ----
#pragma unroll
            for (int it = 0; it < 4; ++it) {
                const int idx = t + (it << 8);
                const int row = idx >> 4;          // 0..63
                const int c4  = (idx & 15) << 2;   // 0..60
                float4 x = make_float4(0.f, 0.f, 0.f, 0.f);
                if (row < C)
                    x = *reinterpret_cast<const float4*>(
                        emb + (size_t)(c0 + row) * ND + c4);
                *reinterpret_cast<float4*>(EF + (row << 6) + c4) = x;
                f16x4 hv, lv;
                const float xa[4] = {x.x, x.y, x.z, x.w};
#pragma unroll
                for (int i = 0; i < 4; ++i) {
                    const _Float16 hh = (_Float16)xa[i];
                    hv[i] = hh;
                    lv[i] = (_Float16)(xa[i] - (float)hh);
                }
                const int woff = (row << 7) + ((c4 << 1) ^ ((row & 7) << 4));
                *reinterpret_cast<f16x4*>((char*)EH + woff) = hv;
                *reinterpret_cast<f16x4*>((char*)EL + woff) = lv;
            }
            __syncthreads();

            // ---- scores for head h over the chunk ----
            const int nvt = (C + 15) >> 4;
            for (int vt = 0; vt < nvt; ++vt) {
                const int row = (vt << 4) + vcol;
                const int rb  = row << 7;
                const int sw  = (row & 7) << 4;
                const f16x8 bh0 = *reinterpret_cast<const f16x8*>(
                    (const char*)EH + rb + (((g << 4)) ^ sw));
                const f16x8 bh1 = *reinterpret_cast<const f16x8*>(
                    (const char*)EH + rb + ((64 | (g << 4)) ^ sw));
                const f16x8 bl0 = *reinterpret_cast<const f16x8*>(
                    (const char*)EL + rb + (((g << 4)) ^ sw));
                const f16x8 bl1 = *reinterpret_cast<const f16x8*>(
                    (const char*)EL + rb + ((64 | (g << 4)) ^ sw));
                float sreg = 0.f;
#pragma unroll
                for (int jt = 0; jt < 4; ++jt) {
                    f32x4 a4 = {0.f, 0.f, 0.f, 0.f};
                    a4 = __builtin_amdgcn_mfma_f32_16x16x32_f16(wh[jt][0], bh0, a4, 0, 0, 0);
                    a4 = __builtin_amdgcn_mfma_f32_16x16x32_f16(wh[jt][1], bh1, a4, 0, 0, 0);
                    a4 = __builtin_amdgcn_mfma_f32_16x16x32_f16(wh[jt][0], bl0, a4, 0, 0, 0);
                    a4 = __builtin_amdgcn_mfma_f32_16x16x32_f16(wh[jt][1], bl1, a4, 0, 0, 0);
                    a4 = __builtin_amdgcn_mfma_f32_16x16x32_f16(wl[jt][0], bh0, a4, 0, 0, 0);
                    a4 = __builtin_amdgcn_mfma_f32_16x16x32_f16(wl[jt][1], bh1, a4, 0, 0, 0);
                    sreg += a4[0]*a4[0] + a4[1]*a4[1] + a4[2]*a4[2] + a4[3]*a4[3];
                }
                sreg += __shfl_xor(sreg, 16, 64);
                sreg += __shfl_xor(sreg, 32, 64);
                if (lane < 16) escore[h][(vt << 4) + lane] = sreg;
            }

            // ---- online softmax update (wave-local; same wave wrote escore) --
            const float sc = (lane < C) ? escore[h][lane] : -1e30f;
            float cmax = sc;
#pragma unroll
            for (int off = 1; off < 64; off <<= 1)
                cmax = fmaxf(cmax, __shfl_xor(cmax, off, 64));
            const float mn = fmaxf(m, cmax);
            const float r  = __expf(m - mn);
            const float e  = (lane < C) ? __expf(sc - mn) : 0.f;
            ee[h][lane] = e;
            float csum = e;
#pragma unroll
            for (int off = 1; off < 64; off <<= 1)
                csum += __shfl_xor(csum, off, 64);
            l = l * r + csum;
            m = mn;
            acc *= r;

            // ---- weighted pooling from LDS ----
#pragma unroll 4
            for (int v = 0; v < C; ++v)
                acc = fmaf(ee[h][v], EF[(v << 6) + lane], acc);

            __syncthreads();   // protect LDS reuse by next chunk/sample
        }
        pooled[(size_t)s * NHID + t] = (en > st) ? acc / l : 0.f;
    }
}

// ---------------------------------------------------------------------------
// Kernel D: out = pooled @ W_out
// ---------------------------------------------------------------------------
__global__ __launch_bounds__(256) void out_kernel(
    const float* __restrict__ pooled, const float* __restrict__ Wout,
    float* __restrict__ out)
{
    __shared__ float Pt[16][260];
    const int t = threadIdx.x;
    const int sbase = blockIdx.x << 4;
#pragma unroll
    for (int it = 0; it < 4; ++it) {
        const int idx = t + (it << 8);
        const int row = idx >> 6;
        const int c4 = (idx & 63) << 2;
        *reinterpret_cast<float4*>(&Pt[row][c4]) =
            *reinterpret_cast<const float4*>(pooled + (size_t)(sbase + row) * NHID + c4);
    }
    __syncthreads();
    const int oc = (t & 31) << 2;
    const int sg = t >> 5;
    float a0x = 0.f, a0y = 0.f, a0z = 0.f, a0w = 0.f;
    float a1x = 0.f, a1y = 0.f, a1z = 0.f, a1w = 0.f;
#pragma unroll 4
    for (int k = 0; k < NHID; ++k) {
        const float4 w = *reinterpret_cast<const float4*>(Wout + (size_t)k * NOUT + oc);
        const float p0 = Pt[(sg << 1) + 0][k];
        const float p1 = Pt[(sg << 1) + 1][k];
        a0x = fmaf(p0, w.x, a0x); a0y = fmaf(p0, w.y, a0y);
        a0z = fmaf(p0, w.z, a0z); a0w = fmaf(p0, w.w, a0w);
        a1x = fmaf(p1, w.x, a1x); a1y = fmaf(p1, w.y, a1y);
        a1z = fmaf(p1, w.z, a1z); a1w = fmaf(p1, w.w, a1w);
    }
    *reinterpret_cast<float4*>(out + (size_t)(sbase + (sg << 1) + 0) * NOUT + oc) =
        make_float4(a0x, a0y, a0z, a0w);
    *reinterpret_cast<float4*>(out + (size_t)(sbase + (sg << 1) + 1) * NOUT + oc) =
        make_float4(a1x, a1y, a1z, a1w);
}

// ---------------------------------------------------------------------------
extern "C" void kernel_launch(void* const* d_in, const int* in_sizes, int n_in,
                              void* d_out, int out_size, void* d_ws, size_t ws_size,
                              hipStream_t stream)
{
    const float* emb  = (const float*)d_in[0];
    const float* Wv   = (const float*)d_in[1];
    const float* Wout = (const float*)d_in[2];
    const int*   map  = (const int*)d_in[3];
    float* out = (float*)d_out;

    char* ws = (char*)d_ws;
    float*    pooled = (float*)ws;                    // 10,240,000 B
    int*      start  = (int*)(ws + 10240000);         //     40,004 B
    _Float16* WtH    = (_Float16*)(ws + 10280064);    //     32,768 B
    _Float16* WtL    = (_Float16*)(ws + 10312832);    //     32,768 B

    wconv_kernel<<<64, 256, 0, stream>>>(Wv, WtH, WtL);
    bounds_kernel<<<(NV + 255) / 256, 256, 0, stream>>>(map, start);
    fused_kernel<<<FUSED_GRID, 256, 0, stream>>>(emb, WtH, WtL, start, pooled);
    out_kernel<<<NS / 16, 256, 0, stream>>>(pooled, Wout, out);
}